// Round 1
// 409.864 us; speedup vs baseline: 1.1197x; 1.1197x over previous
//
#include <hip/hip_runtime.h>

#define B_ 4
#define S_ 2048
#define D_ 1024
#define H_ 16
#define SCALE_ 0.03125f
#define EPS_ 1e-5f
#define NBS_ 8192   // B*S

typedef unsigned short ushort_t;
typedef __attribute__((ext_vector_type(8))) short short8;
typedef __attribute__((ext_vector_type(4))) short short4v;
typedef __attribute__((ext_vector_type(4))) float floatx4;
typedef __attribute__((ext_vector_type(2))) unsigned int uint2v;

__device__ __forceinline__ ushort_t f2bf(float f) {
  union { float f; unsigned u; } v; v.f = f;
  unsigned r = v.u + 0x7fffu + ((v.u >> 16) & 1u);
  return (ushort_t)(r >> 16);
}

__device__ __forceinline__ float fast_exp2(float x) {
#if __has_builtin(__builtin_amdgcn_exp2f)
  return __builtin_amdgcn_exp2f(x);
#else
  return __expf(x * 0.6931471805599453f);
#endif
}

__device__ __forceinline__ short8 cvt8(float4 a, float4 b) {
  short8 r;
  r[0] = (short)f2bf(a.x); r[1] = (short)f2bf(a.y);
  r[2] = (short)f2bf(a.z); r[3] = (short)f2bf(a.w);
  r[4] = (short)f2bf(b.x); r[5] = (short)f2bf(b.y);
  r[6] = (short)f2bf(b.z); r[7] = (short)f2bf(b.w);
  return r;
}

// async global->LDS, 16B per lane; lds dest = wave-uniform base + lane*16
__device__ __forceinline__ void gload16(const void* g, void* l) {
  __builtin_amdgcn_global_load_lds(
      (const __attribute__((address_space(1))) unsigned int*)g,
      (__attribute__((address_space(3))) unsigned int*)l, 16, 0, 0);
}

// ---------------------------------------------------------------------------
// cvtx_k: f32 -> bf16 elementwise (8 elems/thread)
// ---------------------------------------------------------------------------
__global__ __launch_bounds__(256) void cvtx_k(const float* __restrict__ src,
                                              ushort_t* __restrict__ dst)
{
  size_t i = ((size_t)blockIdx.x * 256 + threadIdx.x) * 8;
  float4 a = *(const float4*)(src + i);
  float4 b = *(const float4*)(src + i + 4);
  *(short8*)(dst + i) = cvt8(a, b);
}

// ---------------------------------------------------------------------------
// wtr_k: weight transpose f32 -> bf16 N x K (k-contiguous).
// mode 0: src = W[h][d][n] ([H,1024,64]); dst[c=h*64+n][d]
// mode 1: src = Wo[c][d] ([1024,1024]);  dst[d][c]
// ---------------------------------------------------------------------------
__global__ __launch_bounds__(256) void wtr_k(const float* __restrict__ src,
                                             ushort_t* __restrict__ dst, int mode)
{
  __shared__ float t[64][65];
  const int tr = blockIdx.x, tc = blockIdx.y;
  const float* sb; int sld;
  if (mode == 0) { sb = src + (size_t)tr * 65536 + (size_t)tc * 64 * 64; sld = 64; }
  else           { sb = src + (size_t)tc * 64 * 1024 + (size_t)tr * 64;  sld = 1024; }
  const int tid = threadIdx.x;
  const int rr = tid >> 2, cs = (tid & 3) * 16;
  const float* p = sb + (size_t)rr * sld + cs;
#pragma unroll
  for (int j = 0; j < 16; ++j) t[rr][cs + j] = p[j];
  __syncthreads();
  ushort_t* dp = dst + (size_t)(tr * 64 + rr) * 1024 + tc * 64 + cs;
#pragma unroll
  for (int j = 0; j < 16; ++j) dp[j] = f2bf(t[cs + j][rr]);
}

// ---------------------------------------------------------------------------
// gemm_proj: C[m][c] = (A[m][:].Bw[c][:] + bias[c]) * scale -> [B][H][S][64]
// ---------------------------------------------------------------------------
__global__ __launch_bounds__(256) void gemm_proj(
    const ushort_t* __restrict__ A, const ushort_t* __restrict__ Bw,
    const float* __restrict__ bias, ushort_t* __restrict__ outp, float scale)
{
  __shared__ ushort_t As[128 * 32];
  __shared__ ushort_t Bs[128 * 32];
  const int tid = threadIdx.x;
  const int wv = tid >> 6, lane = tid & 63, quad = lane >> 4, l16 = lane & 15;
  const int m0 = blockIdx.x * 128, n0 = blockIdx.y * 128;
  const int wm = wv & 1, wn = wv >> 1;
  const int lrow = lane >> 2, lkc = (lane & 3) * 8;

  floatx4 acc[4][4];
#pragma unroll
  for (int i = 0; i < 4; ++i)
#pragma unroll
    for (int j = 0; j < 4; ++j) acc[i][j] = (floatx4){0.f, 0.f, 0.f, 0.f};

  for (int k0 = 0; k0 < 1024; k0 += 32) {
    __syncthreads();
#pragma unroll
    for (int j = 0; j < 2; ++j) {
      const int rb = wv * 32 + j * 16;
      gload16(A + (size_t)(m0 + rb + lrow) * 1024 + k0 + lkc, (char*)As + rb * 64);
      gload16(Bw + (size_t)(n0 + rb + lrow) * 1024 + k0 + lkc, (char*)Bs + rb * 64);
    }
    __syncthreads();
    short8 af[4], bf[4];
#pragma unroll
    for (int i = 0; i < 4; ++i)
      af[i] = *(const short8*)&As[(wm * 64 + i * 16 + l16) * 32 + quad * 8];
#pragma unroll
    for (int i = 0; i < 4; ++i)
      bf[i] = *(const short8*)&Bs[(wn * 64 + i * 16 + l16) * 32 + quad * 8];
#pragma unroll
    for (int mi = 0; mi < 4; ++mi)
#pragma unroll
      for (int ni = 0; ni < 4; ++ni)
        acc[mi][ni] = __builtin_amdgcn_mfma_f32_16x16x32_bf16(
            af[mi], bf[ni], acc[mi][ni], 0, 0, 0);
  }

  const int b = m0 >> 11;
  const int sbase = (m0 & 2047) + wm * 64;
#pragma unroll
  for (int ni = 0; ni < 4; ++ni) {
    const int c = n0 + wn * 64 + ni * 16 + l16;
    const int h = c >> 6, nn = c & 63;
    const float bs = bias[c];
    ushort_t* op = outp + (size_t)(b * 16 + h) * 2048 * 64 + nn;
#pragma unroll
    for (int mi = 0; mi < 4; ++mi)
#pragma unroll
      for (int r = 0; r < 4; ++r) {
        int s = sbase + mi * 16 + quad * 4 + r;
        op[(size_t)s * 64] = f2bf((acc[mi][ni][r] + bs) * scale);
      }
  }
}

// ---------------------------------------------------------------------------
// gemm_projT: same GEMM but epilogue writes V^T: out[(b*16+h)][dv][s]
// ---------------------------------------------------------------------------
__global__ __launch_bounds__(256) void gemm_projT(
    const ushort_t* __restrict__ A, const ushort_t* __restrict__ Bw,
    const float* __restrict__ bias, ushort_t* __restrict__ outp)
{
  __shared__ ushort_t As[128 * 32];
  __shared__ ushort_t Bs[128 * 32];
  const int tid = threadIdx.x;
  const int wv = tid >> 6, lane = tid & 63, quad = lane >> 4, l16 = lane & 15;
  const int m0 = blockIdx.x * 128, n0 = blockIdx.y * 128;
  const int wm = wv & 1, wn = wv >> 1;
  const int lrow = lane >> 2, lkc = (lane & 3) * 8;

  floatx4 acc[4][4];
#pragma unroll
  for (int i = 0; i < 4; ++i)
#pragma unroll
    for (int j = 0; j < 4; ++j) acc[i][j] = (floatx4){0.f, 0.f, 0.f, 0.f};

  for (int k0 = 0; k0 < 1024; k0 += 32) {
    __syncthreads();
#pragma unroll
    for (int j = 0; j < 2; ++j) {
      const int rb = wv * 32 + j * 16;
      gload16(A + (size_t)(m0 + rb + lrow) * 1024 + k0 + lkc, (char*)As + rb * 64);
      gload16(Bw + (size_t)(n0 + rb + lrow) * 1024 + k0 + lkc, (char*)Bs + rb * 64);
    }
    __syncthreads();
    short8 af[4], bf[4];
#pragma unroll
    for (int i = 0; i < 4; ++i)
      af[i] = *(const short8*)&As[(wm * 64 + i * 16 + l16) * 32 + quad * 8];
#pragma unroll
    for (int i = 0; i < 4; ++i)
      bf[i] = *(const short8*)&Bs[(wn * 64 + i * 16 + l16) * 32 + quad * 8];
#pragma unroll
    for (int mi = 0; mi < 4; ++mi)
#pragma unroll
      for (int ni = 0; ni < 4; ++ni)
        acc[mi][ni] = __builtin_amdgcn_mfma_f32_16x16x32_bf16(
            af[mi], bf[ni], acc[mi][ni], 0, 0, 0);
  }

  const int b = m0 >> 11;
  const int sbase = (m0 & 2047) + wm * 64;
#pragma unroll
  for (int ni = 0; ni < 4; ++ni) {
    const int c = n0 + wn * 64 + ni * 16 + l16;
    const int h = c >> 6, nn = c & 63;
    const float bs = bias[c];
    ushort_t* op = outp + ((size_t)(b * 16 + h) * 64 + nn) * 2048;
#pragma unroll
    for (int mi = 0; mi < 4; ++mi) {
      int s0v = sbase + mi * 16 + quad * 4;
      short4v p;
#pragma unroll
      for (int r = 0; r < 4; ++r) p[r] = (short)f2bf(acc[mi][ni][r] + bs);
      *(short4v*)(op + s0v) = p;
    }
  }
}

// ---------------------------------------------------------------------------
// gemm_oproj: y[m][d] = ao[m][:].Wt_o[d][:] + bo[d] + resid[m][d]  (f32 out)
// ---------------------------------------------------------------------------
__global__ __launch_bounds__(256) void gemm_oproj(
    const ushort_t* __restrict__ A, const ushort_t* __restrict__ Bw,
    const float* __restrict__ bo, const float* __restrict__ resid,
    float* __restrict__ y)
{
  __shared__ ushort_t As[128 * 32];
  __shared__ ushort_t Bs[128 * 32];
  const int tid = threadIdx.x;
  const int wv = tid >> 6, lane = tid & 63, quad = lane >> 4, l16 = lane & 15;
  const int m0 = blockIdx.x * 128, n0 = blockIdx.y * 128;
  const int wm = wv & 1, wn = wv >> 1;
  const int lrow = lane >> 2, lkc = (lane & 3) * 8;

  floatx4 acc[4][4];
#pragma unroll
  for (int i = 0; i < 4; ++i)
#pragma unroll
    for (int j = 0; j < 4; ++j) acc[i][j] = (floatx4){0.f, 0.f, 0.f, 0.f};

  for (int k0 = 0; k0 < 1024; k0 += 32) {
    __syncthreads();
#pragma unroll
    for (int j = 0; j < 2; ++j) {
      const int rb = wv * 32 + j * 16;
      gload16(A + (size_t)(m0 + rb + lrow) * 1024 + k0 + lkc, (char*)As + rb * 64);
      gload16(Bw + (size_t)(n0 + rb + lrow) * 1024 + k0 + lkc, (char*)Bs + rb * 64);
    }
    __syncthreads();
    short8 af[4], bf[4];
#pragma unroll
    for (int i = 0; i < 4; ++i)
      af[i] = *(const short8*)&As[(wm * 64 + i * 16 + l16) * 32 + quad * 8];
#pragma unroll
    for (int i = 0; i < 4; ++i)
      bf[i] = *(const short8*)&Bs[(wn * 64 + i * 16 + l16) * 32 + quad * 8];
#pragma unroll
    for (int mi = 0; mi < 4; ++mi)
#pragma unroll
      for (int ni = 0; ni < 4; ++ni)
        acc[mi][ni] = __builtin_amdgcn_mfma_f32_16x16x32_bf16(
            af[mi], bf[ni], acc[mi][ni], 0, 0, 0);
  }

  const int mb = m0 + wm * 64;
#pragma unroll
  for (int ni = 0; ni < 4; ++ni) {
    const int d = n0 + wn * 64 + ni * 16 + l16;
    const float bs = bo[d];
#pragma unroll
    for (int mi = 0; mi < 4; ++mi)
#pragma unroll
      for (int r = 0; r < 4; ++r) {
        int m = mb + mi * 16 + quad * 4 + r;
        y[(size_t)m * 1024 + d] = acc[mi][ni][r] + bs + resid[(size_t)m * 1024 + d];
      }
  }
}

// ---------------------------------------------------------------------------
// attn_k v4: swapped QK^T (mfma(K,Q)) -> lane owns a full q-row of P.
//   exp + row-sum lane-local; P packed in-reg to u32 pairs, written as
//   4x ds_write_b64 per rb into XOR-swizzled LDS (byte ^= (q&7)<<4),
//   read back as b128 A-fragments. One lgkmcnt drain per tile (2-slot P).
//   V fragments hoisted (read once per tile, used for both rb).
// LDS byte map: K dbuf [0,16384) | V dbuf [16384,32768) | P [32768,49152)
// ---------------------------------------------------------------------------
__global__ __launch_bounds__(256, 3) void attn_k(
    const ushort_t* __restrict__ q, const ushort_t* __restrict__ k,
    const ushort_t* __restrict__ vt, ushort_t* __restrict__ ao)
{
  __shared__ ushort_t lds[24576];   // 48 KiB
  char* ldsb = (char*)lds;
  const int tid = threadIdx.x;
  const int wv = tid >> 6, lane = tid & 63, quad = lane >> 4, l16 = lane & 15;
  const int q0 = blockIdx.x * 128, h = blockIdx.y, b = blockIdx.z;
  const size_t bh = (size_t)(b * H_ + h) * S_;
  const ushort_t* vb = vt + (size_t)(b * H_ + h) * 64 * S_;

  // Q fragments (held all kernel): aq[rb][half]; q pre-scaled by SCALE*log2e
  short8 aq[2][2];
#pragma unroll
  for (int rb = 0; rb < 2; ++rb) {
    const ushort_t* qrow = q + (bh + q0 + wv * 32 + rb * 16 + l16) * 64;
    aq[rb][0] = *(const short8*)(qrow + quad * 8);
    aq[rb][1] = *(const short8*)(qrow + 32 + quad * 8);
  }

  floatx4 o[2][4];
  float ll[2] = {0.f, 0.f};
#pragma unroll
  for (int rb = 0; rb < 2; ++rb)
#pragma unroll
    for (int cb = 0; cb < 4; ++cb) o[rb][cb] = (floatx4){0.f, 0.f, 0.f, 0.f};

  // P addressing: unswizzled byte of P[q=l16][t] = q*128 + t*2; swizzle
  // XORs (q&7)<<4 on both write and read sides (same involution).
  const int swz = (l16 & 7) << 4;
  const int q8 = quad * 8;
  const int pb = 32768 + wv * 4096 + l16 * 128;   // per-wave, per-row base

  // stage(nb, t0): K block idx -> bytes nb*8192 + idx*1024 (idx = cb*2+hf)
  //                V block     -> bytes 16384 + nb*8192 + (idx-8)*1024
  auto stage = [&](int nb, int t0) {
#pragma unroll
    for (int i = 0; i < 4; ++i) {
      const int idx = wv * 4 + i;
      const int cb = (idx >> 1) & 3, hf = idx & 1;
      if (idx < 8)
        gload16(k + (bh + t0 + cb * 16 + l16) * 64 + hf * 32 + quad * 8,
                (char*)lds + nb * 8192 + idx * 1024);
      else
        gload16(vb + (size_t)(cb * 16 + l16) * S_ + t0 + hf * 32 + quad * 8,
                (char*)lds + 16384 + nb * 8192 + (idx - 8) * 1024);
    }
  };

  stage(0, 0);
  asm volatile("s_waitcnt vmcnt(0)" ::: "memory");
  __syncthreads();

  for (int t0 = 0; t0 < S_; t0 += 64) {
    const int nb = (t0 >> 6) & 1;
    const ushort_t* KsC = lds + nb * 4096;          // ushort offsets
    const ushort_t* VsC = lds + 8192 + nb * 4096;
    if (t0 + 64 < S_) stage(nb ^ 1, t0 + 64);

    // QK^T swapped: sc = mfma(K, Q) -> lane holds S[t=cb*16+quad*4+r][q=l16]
    floatx4 sc[2][4];
#pragma unroll
    for (int rb = 0; rb < 2; ++rb)
#pragma unroll
      for (int cb = 0; cb < 4; ++cb) sc[rb][cb] = (floatx4){0.f, 0.f, 0.f, 0.f};
    __builtin_amdgcn_s_setprio(1);
#pragma unroll
    for (int hf = 0; hf < 2; ++hf) {
      short8 bk[4];
#pragma unroll
      for (int cb = 0; cb < 4; ++cb)
        bk[cb] = *(const short8*)&KsC[(cb * 2 + hf) * 512 + lane * 8];
#pragma unroll
      for (int rb = 0; rb < 2; ++rb)
#pragma unroll
        for (int cb = 0; cb < 4; ++cb)
          sc[rb][cb] = __builtin_amdgcn_mfma_f32_16x16x32_bf16(
              bk[cb], aq[rb][hf], sc[rb][cb], 0, 0, 0);
    }
    __builtin_amdgcn_s_setprio(0);

    // V fragments once per tile (both hf, both rb use them)
    short8 bvf[2][4];
#pragma unroll
    for (int hf = 0; hf < 2; ++hf)
#pragma unroll
      for (int cb = 0; cb < 4; ++cb)
        bvf[hf][cb] = *(const short8*)&VsC[(cb * 2 + hf) * 512 + lane * 8];

    // exp2 + lane-local row-sum + pack pairs -> 4x ds_write_b64 per rb
#pragma unroll
    for (int rb = 0; rb < 2; ++rb) {
#pragma unroll
      for (int cb = 0; cb < 4; ++cb) {
        float p0 = fast_exp2(sc[rb][cb][0]);
        float p1 = fast_exp2(sc[rb][cb][1]);
        float p2 = fast_exp2(sc[rb][cb][2]);
        float p3 = fast_exp2(sc[rb][cb][3]);
        ll[rb] += (p0 + p1) + (p2 + p3);
        uint2v w;
        w[0] = (unsigned)f2bf(p0) | ((unsigned)f2bf(p1) << 16);
        w[1] = (unsigned)f2bf(p2) | ((unsigned)f2bf(p3) << 16);
        *(uint2v*)(ldsb + pb + rb * 2048 + ((cb * 32 + q8) ^ swz)) = w;
      }
    }
    asm volatile("s_waitcnt lgkmcnt(0)" ::: "memory");
    __builtin_amdgcn_sched_barrier(0);

    // PV: ap = A-fragment of P (row q=l16, k = hf*32+quad*8+j)
    __builtin_amdgcn_s_setprio(1);
#pragma unroll
    for (int rb = 0; rb < 2; ++rb)
#pragma unroll
      for (int hf = 0; hf < 2; ++hf) {
        short8 ap = *(const short8*)(ldsb + pb + rb * 2048 +
                                     ((hf * 64 + quad * 16) ^ swz));
#pragma unroll
        for (int cb = 0; cb < 4; ++cb)
          o[rb][cb] = __builtin_amdgcn_mfma_f32_16x16x32_bf16(
              ap, bvf[hf][cb], o[rb][cb], 0, 0, 0);
      }
    __builtin_amdgcn_s_setprio(0);

    asm volatile("s_waitcnt vmcnt(0)" ::: "memory");  // prefetch landed
    __syncthreads();
  }

  // epilogue: ll holds per-lane partial row-sum for q=l16 (this quad's t's).
  // Sum across quads (lanes ^16, ^32), then fetch per-output-row inverse.
#pragma unroll
  for (int rb = 0; rb < 2; ++rb) {
    ll[rb] += __shfl_xor(ll[rb], 16);
    ll[rb] += __shfl_xor(ll[rb], 32);
  }
  float linv[2][4];
#pragma unroll
  for (int rb = 0; rb < 2; ++rb)
#pragma unroll
    for (int r = 0; r < 4; ++r)
      linv[rb][r] = 1.f / __shfl(ll[rb], quad * 4 + r);
#pragma unroll
  for (int rb = 0; rb < 2; ++rb)
#pragma unroll
    for (int cb = 0; cb < 4; ++cb)
#pragma unroll
      for (int r = 0; r < 4; ++r) {
        float val = o[rb][cb][r] * linv[rb][r];
        size_t idx = (size_t)(b * S_ + q0 + wv * 32 + rb * 16 + quad * 4 + r) * 1024
                     + h * 64 + cb * 16 + l16;
        ao[idx] = f2bf(val);
      }
}

// ---------------------------------------------------------------------------
// K4: per-channel sum / sumsq over 8192 samples.
// ---------------------------------------------------------------------------
__global__ __launch_bounds__(256) void stats_k(
    const float* __restrict__ y, float* __restrict__ s1, float* __restrict__ s2)
{
  const int tid = threadIdx.x;
  const int r0 = blockIdx.x * 32;
  float a[4] = {0.f, 0.f, 0.f, 0.f}, bb[4] = {0.f, 0.f, 0.f, 0.f};
  for (int r = 0; r < 32; ++r) {
    const float* row = y + (size_t)(r0 + r) * D_;
#pragma unroll
    for (int j = 0; j < 4; ++j) {
      float vv = row[tid + j * 256];
      a[j] += vv;
      bb[j] += vv * vv;
    }
  }
#pragma unroll
  for (int j = 0; j < 4; ++j) {
    atomicAdd(&s1[tid + j * 256], a[j]);
    atomicAdd(&s2[tid + j * 256], bb[j]);
  }
}

// ---------------------------------------------------------------------------
// K5: batchnorm affine + 64x64 transpose -> out[b][d][s] (f32)
// ---------------------------------------------------------------------------
__global__ __launch_bounds__(256) void norm_k(
    const float* __restrict__ y, const float* __restrict__ s1,
    const float* __restrict__ s2, const float* __restrict__ gamma,
    const float* __restrict__ beta, float* __restrict__ out)
{
  __shared__ float tile[64][65];
  __shared__ float scl[64], sft[64];
  const int tid = threadIdx.x;
  const int s0 = blockIdx.x * 64, d0 = blockIdx.y * 64, b = blockIdx.z;

  if (tid < 64) {
    int d = d0 + tid;
    float mean = s1[d] * (1.f / (float)NBS_);
    float var = s2[d] * (1.f / (float)NBS_) - mean * mean;
    float rstd = rsqrtf(var + EPS_);
    float g = gamma[d];
    scl[tid] = rstd * g;
    sft[tid] = beta[d] - mean * rstd * g;
  }
  __syncthreads();

  const int si = tid >> 2, dc = (tid & 3) * 16;
  const float* row = y + (size_t)(b * S_ + s0 + si) * D_ + d0 + dc;
#pragma unroll
  for (int j = 0; j < 16; ++j)
    tile[si][dc + j] = row[j] * scl[dc + j] + sft[dc + j];
  __syncthreads();

  const int di = tid >> 2, sg = (tid & 3) * 16;
  float* dst = out + (size_t)(b * D_ + d0 + di) * S_ + s0 + sg;
#pragma unroll
  for (int jj = 0; jj < 4; ++jj) {
    float4 p;
    p.x = tile[sg + jj * 4 + 0][di];
    p.y = tile[sg + jj * 4 + 1][di];
    p.z = tile[sg + jj * 4 + 2][di];
    p.w = tile[sg + jj * 4 + 3][di];
    *(float4*)(dst + jj * 4) = p;
  }
}

// ---------------------------------------------------------------------------
extern "C" void kernel_launch(void* const* d_in, const int* in_sizes, int n_in,
                              void* d_out, int out_size, void* d_ws, size_t ws_size,
                              hipStream_t stream)
{
  (void)in_sizes; (void)n_in; (void)out_size; (void)ws_size;
  const float* Q     = (const float*)d_in[0];
  const float* Kin   = (const float*)d_in[1];
  const float* Vin   = (const float*)d_in[2];
  const float* Wq    = (const float*)d_in[3];
  const float* bq    = (const float*)d_in[4];
  const float* Wk    = (const float*)d_in[5];
  const float* bk    = (const float*)d_in[6];
  const float* Wv    = (const float*)d_in[7];
  const float* bv    = (const float*)d_in[8];
  const float* Wo    = (const float*)d_in[9];
  const float* bo    = (const float*)d_in[10];
  const float* gamma = (const float*)d_in[11];
  const float* beta  = (const float*)d_in[12];
  float* out = (float*)d_out;

  char* ws = (char*)d_ws;
  const size_t MB = 1u << 20;
  ushort_t* xb  = (ushort_t*)(ws);
  ushort_t* wtq = (ushort_t*)(ws + 16 * MB);
  ushort_t* wtk = (ushort_t*)(ws + 18 * MB);
  ushort_t* wtv = (ushort_t*)(ws + 20 * MB);
  ushort_t* wto = (ushort_t*)(ws + 22 * MB);
  ushort_t* qb  = (ushort_t*)(ws + 24 * MB);
  ushort_t* kb  = (ushort_t*)(ws + 40 * MB);
  ushort_t* vtb = (ushort_t*)(ws + 56 * MB);
  ushort_t* ao  = (ushort_t*)(ws);
  float*    y   = (float*)(ws + 24 * MB);
  float*    s1  = (float*)(ws + 56 * MB);
  float*    s2  = (float*)(ws + 56 * MB + 4096);

  wtr_k<<<dim3(16, 16), 256, 0, stream>>>(Wq, wtq, 0);
  wtr_k<<<dim3(16, 16), 256, 0, stream>>>(Wk, wtk, 0);
  wtr_k<<<dim3(16, 16), 256, 0, stream>>>(Wv, wtv, 0);
  wtr_k<<<dim3(16, 16), 256, 0, stream>>>(Wo, wto, 1);

  // q pre-scaled by SCALE*log2(e) so attention logits are already exp2-domain
  const float QSC = SCALE_ * 1.44269504088896f;
  cvtx_k<<<4096, 256, 0, stream>>>(Q, xb);
  gemm_proj<<<dim3(64, 8), 256, 0, stream>>>(xb, wtq, bq, qb, QSC);
  cvtx_k<<<4096, 256, 0, stream>>>(Kin, xb);
  gemm_proj<<<dim3(64, 8), 256, 0, stream>>>(xb, wtk, bk, kb, 1.0f);
  cvtx_k<<<4096, 256, 0, stream>>>(Vin, xb);
  gemm_projT<<<dim3(64, 8), 256, 0, stream>>>(xb, wtv, bv, vtb);

  attn_k<<<dim3(16, 16, 4), 256, 0, stream>>>(qb, kb, vtb, ao);
  gemm_oproj<<<dim3(64, 8), 256, 0, stream>>>(ao, wto, bo, Q, y);

  hipMemsetAsync(ws + 56 * MB, 0, 8192, stream);
  stats_k<<<256, 256, 0, stream>>>(y, s1, s2);
  norm_k<<<dim3(32, 16, 4), 256, 0, stream>>>(y, s1, s2, gamma, beta, out);
}

// Round 2
// 400.601 us; speedup vs baseline: 1.1456x; 1.0231x over previous
//
#include <hip/hip_runtime.h>

#define B_ 4
#define S_ 2048
#define D_ 1024
#define H_ 16
#define SCALE_ 0.03125f
#define EPS_ 1e-5f
#define NBS_ 8192   // B*S

typedef unsigned short ushort_t;
typedef __attribute__((ext_vector_type(8))) short short8;
typedef __attribute__((ext_vector_type(4))) short short4v;
typedef __attribute__((ext_vector_type(4))) float floatx4;
typedef __attribute__((ext_vector_type(2))) unsigned int uint2v;

__device__ __forceinline__ ushort_t f2bf(float f) {
  union { float f; unsigned u; } v; v.f = f;
  unsigned r = v.u + 0x7fffu + ((v.u >> 16) & 1u);
  return (ushort_t)(r >> 16);
}

__device__ __forceinline__ float fast_exp2(float x) {
#if __has_builtin(__builtin_amdgcn_exp2f)
  return __builtin_amdgcn_exp2f(x);
#else
  return __expf(x * 0.6931471805599453f);
#endif
}

// packed f32x2 -> bf16x2 (RNE), one VALU op; src0 -> low half
__device__ __forceinline__ unsigned cvt_pk_bf16(float a, float b) {
  unsigned r;
  asm("v_cvt_pk_bf16_f32 %0, %1, %2" : "=v"(r) : "v"(a), "v"(b));
  return r;
}

__device__ __forceinline__ short8 cvt8(float4 a, float4 b) {
  short8 r;
  r[0] = (short)f2bf(a.x); r[1] = (short)f2bf(a.y);
  r[2] = (short)f2bf(a.z); r[3] = (short)f2bf(a.w);
  r[4] = (short)f2bf(b.x); r[5] = (short)f2bf(b.y);
  r[6] = (short)f2bf(b.z); r[7] = (short)f2bf(b.w);
  return r;
}

// async global->LDS, 16B per lane; lds dest = wave-uniform base + lane*16
__device__ __forceinline__ void gload16(const void* g, void* l) {
  __builtin_amdgcn_global_load_lds(
      (const __attribute__((address_space(1))) unsigned int*)g,
      (__attribute__((address_space(3))) unsigned int*)l, 16, 0, 0);
}

// ---------------------------------------------------------------------------
// cvtx_k: f32 -> bf16 elementwise (8 elems/thread)
// ---------------------------------------------------------------------------
__global__ __launch_bounds__(256) void cvtx_k(const float* __restrict__ src,
                                              ushort_t* __restrict__ dst)
{
  size_t i = ((size_t)blockIdx.x * 256 + threadIdx.x) * 8;
  float4 a = *(const float4*)(src + i);
  float4 b = *(const float4*)(src + i + 4);
  *(short8*)(dst + i) = cvt8(a, b);
}

// ---------------------------------------------------------------------------
// wtr_k: weight transpose f32 -> bf16 N x K (k-contiguous).
// mode 0: src = W[h][d][n] ([H,1024,64]); dst[c=h*64+n][d]
// mode 1: src = Wo[c][d] ([1024,1024]);  dst[d][c]
// ---------------------------------------------------------------------------
__global__ __launch_bounds__(256) void wtr_k(const float* __restrict__ src,
                                             ushort_t* __restrict__ dst, int mode)
{
  __shared__ float t[64][65];
  const int tr = blockIdx.x, tc = blockIdx.y;
  const float* sb; int sld;
  if (mode == 0) { sb = src + (size_t)tr * 65536 + (size_t)tc * 64 * 64; sld = 64; }
  else           { sb = src + (size_t)tc * 64 * 1024 + (size_t)tr * 64;  sld = 1024; }
  const int tid = threadIdx.x;
  const int rr = tid >> 2, cs = (tid & 3) * 16;
  const float* p = sb + (size_t)rr * sld + cs;
#pragma unroll
  for (int j = 0; j < 16; ++j) t[rr][cs + j] = p[j];
  __syncthreads();
  ushort_t* dp = dst + (size_t)(tr * 64 + rr) * 1024 + tc * 64 + cs;
#pragma unroll
  for (int j = 0; j < 16; ++j) dp[j] = f2bf(t[cs + j][rr]);
}

// ---------------------------------------------------------------------------
// gemm_proj: C[m][c] = (A[m][:].Bw[c][:] + bias[c]) * scale -> [B][H][S][64]
// ---------------------------------------------------------------------------
__global__ __launch_bounds__(256) void gemm_proj(
    const ushort_t* __restrict__ A, const ushort_t* __restrict__ Bw,
    const float* __restrict__ bias, ushort_t* __restrict__ outp, float scale)
{
  __shared__ ushort_t As[128 * 32];
  __shared__ ushort_t Bs[128 * 32];
  const int tid = threadIdx.x;
  const int wv = tid >> 6, lane = tid & 63, quad = lane >> 4, l16 = lane & 15;
  const int m0 = blockIdx.x * 128, n0 = blockIdx.y * 128;
  const int wm = wv & 1, wn = wv >> 1;
  const int lrow = lane >> 2, lkc = (lane & 3) * 8;

  floatx4 acc[4][4];
#pragma unroll
  for (int i = 0; i < 4; ++i)
#pragma unroll
    for (int j = 0; j < 4; ++j) acc[i][j] = (floatx4){0.f, 0.f, 0.f, 0.f};

  for (int k0 = 0; k0 < 1024; k0 += 32) {
    __syncthreads();
#pragma unroll
    for (int j = 0; j < 2; ++j) {
      const int rb = wv * 32 + j * 16;
      gload16(A + (size_t)(m0 + rb + lrow) * 1024 + k0 + lkc, (char*)As + rb * 64);
      gload16(Bw + (size_t)(n0 + rb + lrow) * 1024 + k0 + lkc, (char*)Bs + rb * 64);
    }
    __syncthreads();
    short8 af[4], bf[4];
#pragma unroll
    for (int i = 0; i < 4; ++i)
      af[i] = *(const short8*)&As[(wm * 64 + i * 16 + l16) * 32 + quad * 8];
#pragma unroll
    for (int i = 0; i < 4; ++i)
      bf[i] = *(const short8*)&Bs[(wn * 64 + i * 16 + l16) * 32 + quad * 8];
#pragma unroll
    for (int mi = 0; mi < 4; ++mi)
#pragma unroll
      for (int ni = 0; ni < 4; ++ni)
        acc[mi][ni] = __builtin_amdgcn_mfma_f32_16x16x32_bf16(
            af[mi], bf[ni], acc[mi][ni], 0, 0, 0);
  }

  const int b = m0 >> 11;
  const int sbase = (m0 & 2047) + wm * 64;
#pragma unroll
  for (int ni = 0; ni < 4; ++ni) {
    const int c = n0 + wn * 64 + ni * 16 + l16;
    const int h = c >> 6, nn = c & 63;
    const float bs = bias[c];
    ushort_t* op = outp + (size_t)(b * 16 + h) * 2048 * 64 + nn;
#pragma unroll
    for (int mi = 0; mi < 4; ++mi)
#pragma unroll
      for (int r = 0; r < 4; ++r) {
        int s = sbase + mi * 16 + quad * 4 + r;
        op[(size_t)s * 64] = f2bf((acc[mi][ni][r] + bs) * scale);
      }
  }
}

// ---------------------------------------------------------------------------
// gemm_projT: same GEMM but epilogue writes V^T: out[(b*16+h)][dv][s]
// ---------------------------------------------------------------------------
__global__ __launch_bounds__(256) void gemm_projT(
    const ushort_t* __restrict__ A, const ushort_t* __restrict__ Bw,
    const float* __restrict__ bias, ushort_t* __restrict__ outp)
{
  __shared__ ushort_t As[128 * 32];
  __shared__ ushort_t Bs[128 * 32];
  const int tid = threadIdx.x;
  const int wv = tid >> 6, lane = tid & 63, quad = lane >> 4, l16 = lane & 15;
  const int m0 = blockIdx.x * 128, n0 = blockIdx.y * 128;
  const int wm = wv & 1, wn = wv >> 1;
  const int lrow = lane >> 2, lkc = (lane & 3) * 8;

  floatx4 acc[4][4];
#pragma unroll
  for (int i = 0; i < 4; ++i)
#pragma unroll
    for (int j = 0; j < 4; ++j) acc[i][j] = (floatx4){0.f, 0.f, 0.f, 0.f};

  for (int k0 = 0; k0 < 1024; k0 += 32) {
    __syncthreads();
#pragma unroll
    for (int j = 0; j < 2; ++j) {
      const int rb = wv * 32 + j * 16;
      gload16(A + (size_t)(m0 + rb + lrow) * 1024 + k0 + lkc, (char*)As + rb * 64);
      gload16(Bw + (size_t)(n0 + rb + lrow) * 1024 + k0 + lkc, (char*)Bs + rb * 64);
    }
    __syncthreads();
    short8 af[4], bf[4];
#pragma unroll
    for (int i = 0; i < 4; ++i)
      af[i] = *(const short8*)&As[(wm * 64 + i * 16 + l16) * 32 + quad * 8];
#pragma unroll
    for (int i = 0; i < 4; ++i)
      bf[i] = *(const short8*)&Bs[(wn * 64 + i * 16 + l16) * 32 + quad * 8];
#pragma unroll
    for (int mi = 0; mi < 4; ++mi)
#pragma unroll
      for (int ni = 0; ni < 4; ++ni)
        acc[mi][ni] = __builtin_amdgcn_mfma_f32_16x16x32_bf16(
            af[mi], bf[ni], acc[mi][ni], 0, 0, 0);
  }

  const int b = m0 >> 11;
  const int sbase = (m0 & 2047) + wm * 64;
#pragma unroll
  for (int ni = 0; ni < 4; ++ni) {
    const int c = n0 + wn * 64 + ni * 16 + l16;
    const int h = c >> 6, nn = c & 63;
    const float bs = bias[c];
    ushort_t* op = outp + ((size_t)(b * 16 + h) * 64 + nn) * 2048;
#pragma unroll
    for (int mi = 0; mi < 4; ++mi) {
      int s0v = sbase + mi * 16 + quad * 4;
      short4v p;
#pragma unroll
      for (int r = 0; r < 4; ++r) p[r] = (short)f2bf(acc[mi][ni][r] + bs);
      *(short4v*)(op + s0v) = p;
    }
  }
}

// ---------------------------------------------------------------------------
// gemm_oproj: y[m][d] = ao[m][:].Wt_o[d][:] + bo[d] + resid[m][d]  (f32 out)
// ---------------------------------------------------------------------------
__global__ __launch_bounds__(256) void gemm_oproj(
    const ushort_t* __restrict__ A, const ushort_t* __restrict__ Bw,
    const float* __restrict__ bo, const float* __restrict__ resid,
    float* __restrict__ y)
{
  __shared__ ushort_t As[128 * 32];
  __shared__ ushort_t Bs[128 * 32];
  const int tid = threadIdx.x;
  const int wv = tid >> 6, lane = tid & 63, quad = lane >> 4, l16 = lane & 15;
  const int m0 = blockIdx.x * 128, n0 = blockIdx.y * 128;
  const int wm = wv & 1, wn = wv >> 1;
  const int lrow = lane >> 2, lkc = (lane & 3) * 8;

  floatx4 acc[4][4];
#pragma unroll
  for (int i = 0; i < 4; ++i)
#pragma unroll
    for (int j = 0; j < 4; ++j) acc[i][j] = (floatx4){0.f, 0.f, 0.f, 0.f};

  for (int k0 = 0; k0 < 1024; k0 += 32) {
    __syncthreads();
#pragma unroll
    for (int j = 0; j < 2; ++j) {
      const int rb = wv * 32 + j * 16;
      gload16(A + (size_t)(m0 + rb + lrow) * 1024 + k0 + lkc, (char*)As + rb * 64);
      gload16(Bw + (size_t)(n0 + rb + lrow) * 1024 + k0 + lkc, (char*)Bs + rb * 64);
    }
    __syncthreads();
    short8 af[4], bf[4];
#pragma unroll
    for (int i = 0; i < 4; ++i)
      af[i] = *(const short8*)&As[(wm * 64 + i * 16 + l16) * 32 + quad * 8];
#pragma unroll
    for (int i = 0; i < 4; ++i)
      bf[i] = *(const short8*)&Bs[(wn * 64 + i * 16 + l16) * 32 + quad * 8];
#pragma unroll
    for (int mi = 0; mi < 4; ++mi)
#pragma unroll
      for (int ni = 0; ni < 4; ++ni)
        acc[mi][ni] = __builtin_amdgcn_mfma_f32_16x16x32_bf16(
            af[mi], bf[ni], acc[mi][ni], 0, 0, 0);
  }

  const int mb = m0 + wm * 64;
#pragma unroll
  for (int ni = 0; ni < 4; ++ni) {
    const int d = n0 + wn * 64 + ni * 16 + l16;
    const float bs = bo[d];
#pragma unroll
    for (int mi = 0; mi < 4; ++mi)
#pragma unroll
      for (int r = 0; r < 4; ++r) {
        int m = mb + mi * 16 + quad * 4 + r;
        y[(size_t)m * 1024 + d] = acc[mi][ni][r] + bs + resid[(size_t)m * 1024 + d];
      }
  }
}

// ---------------------------------------------------------------------------
// attn_k v5: swapped QK^T; P packed via v_cvt_pk_bf16_f32 (1 op / 2 vals);
//   P swizzle now includes bit3 (swz = ((l16&7)<<4)|(l16&8)) -> writes AND
//   reads conflict-free; P reads are 2x ds_read_b64 (lo, lo^8).
//   Row-sum ll computed by ones-MFMA (accl += mfma(ap, ones)) -> no VALU
//   adds in loop, no epilogue shuffles (D-row layout == linv indexing).
// LDS byte map: K dbuf [0,16384) | V dbuf [16384,32768) | P [32768,49152)
// ---------------------------------------------------------------------------
__global__ __launch_bounds__(256, 3) void attn_k(
    const ushort_t* __restrict__ q, const ushort_t* __restrict__ k,
    const ushort_t* __restrict__ vt, ushort_t* __restrict__ ao)
{
  __shared__ ushort_t lds[24576];   // 48 KiB
  char* ldsb = (char*)lds;
  const int tid = threadIdx.x;
  const int wv = tid >> 6, lane = tid & 63, quad = lane >> 4, l16 = lane & 15;
  const int q0 = blockIdx.x * 128, h = blockIdx.y, b = blockIdx.z;
  const size_t bh = (size_t)(b * H_ + h) * S_;
  const ushort_t* vb = vt + (size_t)(b * H_ + h) * 64 * S_;

  // Q fragments (held all kernel): aq[rb][half]; q pre-scaled by SCALE*log2e
  short8 aq[2][2];
#pragma unroll
  for (int rb = 0; rb < 2; ++rb) {
    const ushort_t* qrow = q + (bh + q0 + wv * 32 + rb * 16 + l16) * 64;
    aq[rb][0] = *(const short8*)(qrow + quad * 8);
    aq[rb][1] = *(const short8*)(qrow + 32 + quad * 8);
  }

  // all-ones bf16 B fragment for the row-sum MFMA
  short8 ones;
#pragma unroll
  for (int j = 0; j < 8; ++j) ones[j] = (short)0x3F80;

  floatx4 o[2][4];
  floatx4 accl[2];
#pragma unroll
  for (int rb = 0; rb < 2; ++rb) {
#pragma unroll
    for (int cb = 0; cb < 4; ++cb) o[rb][cb] = (floatx4){0.f, 0.f, 0.f, 0.f};
    accl[rb] = (floatx4){0.f, 0.f, 0.f, 0.f};
  }

  // P addressing: unswizzled byte of P[q=l16][t] = q*128 + t*2; swizzle
  // XORs bits 3..6 with row bits -> every 16-lane group covers all 32 banks
  // on both the b64 writes and the b64 reads.
  const int swz = ((l16 & 7) << 4) | (l16 & 8);
  const int q8 = quad * 8;
  const int pb = 32768 + wv * 4096 + l16 * 128;   // per-wave, per-row base

  // stage(nb, t0): K block idx -> bytes nb*8192 + idx*1024 (idx = cb*2+hf)
  //                V block     -> bytes 16384 + nb*8192 + (idx-8)*1024
  auto stage = [&](int nb, int t0) {
#pragma unroll
    for (int i = 0; i < 4; ++i) {
      const int idx = wv * 4 + i;
      const int cb = (idx >> 1) & 3, hf = idx & 1;
      if (idx < 8)
        gload16(k + (bh + t0 + cb * 16 + l16) * 64 + hf * 32 + quad * 8,
                (char*)lds + nb * 8192 + idx * 1024);
      else
        gload16(vb + (size_t)(cb * 16 + l16) * S_ + t0 + hf * 32 + quad * 8,
                (char*)lds + 16384 + nb * 8192 + (idx - 8) * 1024);
    }
  };

  stage(0, 0);
  asm volatile("s_waitcnt vmcnt(0)" ::: "memory");
  __syncthreads();

  for (int t0 = 0; t0 < S_; t0 += 64) {
    const int nb = (t0 >> 6) & 1;
    const ushort_t* KsC = lds + nb * 4096;          // ushort offsets
    const ushort_t* VsC = lds + 8192 + nb * 4096;
    if (t0 + 64 < S_) stage(nb ^ 1, t0 + 64);

    // QK^T swapped: sc = mfma(K, Q) -> lane holds S[t=cb*16+quad*4+r][q=l16]
    floatx4 sc[2][4];
#pragma unroll
    for (int rb = 0; rb < 2; ++rb)
#pragma unroll
      for (int cb = 0; cb < 4; ++cb) sc[rb][cb] = (floatx4){0.f, 0.f, 0.f, 0.f};
    __builtin_amdgcn_s_setprio(1);
#pragma unroll
    for (int hf = 0; hf < 2; ++hf) {
      short8 bk[4];
#pragma unroll
      for (int cb = 0; cb < 4; ++cb)
        bk[cb] = *(const short8*)&KsC[(cb * 2 + hf) * 512 + lane * 8];
#pragma unroll
      for (int rb = 0; rb < 2; ++rb)
#pragma unroll
        for (int cb = 0; cb < 4; ++cb)
          sc[rb][cb] = __builtin_amdgcn_mfma_f32_16x16x32_bf16(
              bk[cb], aq[rb][hf], sc[rb][cb], 0, 0, 0);
    }
    __builtin_amdgcn_s_setprio(0);

    // V fragments once per tile (both hf, both rb use them)
    short8 bvf[2][4];
#pragma unroll
    for (int hf = 0; hf < 2; ++hf)
#pragma unroll
      for (int cb = 0; cb < 4; ++cb)
        bvf[hf][cb] = *(const short8*)&VsC[(cb * 2 + hf) * 512 + lane * 8];

    // exp2 + packed cvt -> 4x ds_write_b64 per rb (conflict-free swizzle)
#pragma unroll
    for (int rb = 0; rb < 2; ++rb)
#pragma unroll
      for (int cb = 0; cb < 4; ++cb) {
        float p0 = fast_exp2(sc[rb][cb][0]);
        float p1 = fast_exp2(sc[rb][cb][1]);
        float p2 = fast_exp2(sc[rb][cb][2]);
        float p3 = fast_exp2(sc[rb][cb][3]);
        uint2v w;
        w[0] = cvt_pk_bf16(p0, p1);
        w[1] = cvt_pk_bf16(p2, p3);
        *(uint2v*)(ldsb + pb + rb * 2048 + ((cb * 32 + q8) ^ swz)) = w;
      }
    asm volatile("s_waitcnt lgkmcnt(0)" ::: "memory");
    __builtin_amdgcn_sched_barrier(0);

    // PV + row-sum: ap = A-fragment of P (row q=l16, k = hf*32+quad*8+j)
    __builtin_amdgcn_s_setprio(1);
#pragma unroll
    for (int rb = 0; rb < 2; ++rb)
#pragma unroll
      for (int hf = 0; hf < 2; ++hf) {
        const char* pr = ldsb + pb + rb * 2048;
        const int lo = (hf * 64 + quad * 16) ^ swz;
        short4v a0 = *(const short4v*)(pr + lo);
        short4v a1 = *(const short4v*)(pr + (lo ^ 8));
        short8 ap;
        ap[0] = a0[0]; ap[1] = a0[1]; ap[2] = a0[2]; ap[3] = a0[3];
        ap[4] = a1[0]; ap[5] = a1[1]; ap[6] = a1[2]; ap[7] = a1[3];
#pragma unroll
        for (int cb = 0; cb < 4; ++cb)
          o[rb][cb] = __builtin_amdgcn_mfma_f32_16x16x32_bf16(
              ap, bvf[hf][cb], o[rb][cb], 0, 0, 0);
        accl[rb] = __builtin_amdgcn_mfma_f32_16x16x32_bf16(
            ap, ones, accl[rb], 0, 0, 0);
      }
    __builtin_amdgcn_s_setprio(0);

    asm volatile("s_waitcnt vmcnt(0)" ::: "memory");  // prefetch landed
    __syncthreads();
  }

  // epilogue: accl[rb][r] = full row sum for q-row quad*4+r (+rb*16+wv*32).
  float linv[2][4];
#pragma unroll
  for (int rb = 0; rb < 2; ++rb)
#pragma unroll
    for (int r = 0; r < 4; ++r)
      linv[rb][r] = 1.f / accl[rb][r];
#pragma unroll
  for (int rb = 0; rb < 2; ++rb)
#pragma unroll
    for (int cb = 0; cb < 4; ++cb)
#pragma unroll
      for (int r = 0; r < 4; ++r) {
        float val = o[rb][cb][r] * linv[rb][r];
        size_t idx = (size_t)(b * S_ + q0 + wv * 32 + rb * 16 + quad * 4 + r) * 1024
                     + h * 64 + cb * 16 + l16;
        ao[idx] = f2bf(val);
      }
}

// ---------------------------------------------------------------------------
// K4: per-channel sum / sumsq over 8192 samples.
// ---------------------------------------------------------------------------
__global__ __launch_bounds__(256) void stats_k(
    const float* __restrict__ y, float* __restrict__ s1, float* __restrict__ s2)
{
  const int tid = threadIdx.x;
  const int r0 = blockIdx.x * 32;
  float a[4] = {0.f, 0.f, 0.f, 0.f}, bb[4] = {0.f, 0.f, 0.f, 0.f};
  for (int r = 0; r < 32; ++r) {
    const float* row = y + (size_t)(r0 + r) * D_;
#pragma unroll
    for (int j = 0; j < 4; ++j) {
      float vv = row[tid + j * 256];
      a[j] += vv;
      bb[j] += vv * vv;
    }
  }
#pragma unroll
  for (int j = 0; j < 4; ++j) {
    atomicAdd(&s1[tid + j * 256], a[j]);
    atomicAdd(&s2[tid + j * 256], bb[j]);
  }
}

// ---------------------------------------------------------------------------
// K5: batchnorm affine + 64x64 transpose -> out[b][d][s] (f32)
// ---------------------------------------------------------------------------
__global__ __launch_bounds__(256) void norm_k(
    const float* __restrict__ y, const float* __restrict__ s1,
    const float* __restrict__ s2, const float* __restrict__ gamma,
    const float* __restrict__ beta, float* __restrict__ out)
{
  __shared__ float tile[64][65];
  __shared__ float scl[64], sft[64];
  const int tid = threadIdx.x;
  const int s0 = blockIdx.x * 64, d0 = blockIdx.y * 64, b = blockIdx.z;

  if (tid < 64) {
    int d = d0 + tid;
    float mean = s1[d] * (1.f / (float)NBS_);
    float var = s2[d] * (1.f / (float)NBS_) - mean * mean;
    float rstd = rsqrtf(var + EPS_);
    float g = gamma[d];
    scl[tid] = rstd * g;
    sft[tid] = beta[d] - mean * rstd * g;
  }
  __syncthreads();

  const int si = tid >> 2, dc = (tid & 3) * 16;
  const float* row = y + (size_t)(b * S_ + s0 + si) * D_ + d0 + dc;
#pragma unroll
  for (int j = 0; j < 16; ++j)
    tile[si][dc + j] = row[j] * scl[dc + j] + sft[dc + j];
  __syncthreads();

  const int di = tid >> 2, sg = (tid & 3) * 16;
  float* dst = out + (size_t)(b * D_ + d0 + di) * S_ + s0 + sg;
#pragma unroll
  for (int jj = 0; jj < 4; ++jj) {
    float4 p;
    p.x = tile[sg + jj * 4 + 0][di];
    p.y = tile[sg + jj * 4 + 1][di];
    p.z = tile[sg + jj * 4 + 2][di];
    p.w = tile[sg + jj * 4 + 3][di];
    *(float4*)(dst + jj * 4) = p;
  }
}

// ---------------------------------------------------------------------------
extern "C" void kernel_launch(void* const* d_in, const int* in_sizes, int n_in,
                              void* d_out, int out_size, void* d_ws, size_t ws_size,
                              hipStream_t stream)
{
  (void)in_sizes; (void)n_in; (void)out_size; (void)ws_size;
  const float* Q     = (const float*)d_in[0];
  const float* Kin   = (const float*)d_in[1];
  const float* Vin   = (const float*)d_in[2];
  const float* Wq    = (const float*)d_in[3];
  const float* bq    = (const float*)d_in[4];
  const float* Wk    = (const float*)d_in[5];
  const float* bk    = (const float*)d_in[6];
  const float* Wv    = (const float*)d_in[7];
  const float* bv    = (const float*)d_in[8];
  const float* Wo    = (const float*)d_in[9];
  const float* bo    = (const float*)d_in[10];
  const float* gamma = (const float*)d_in[11];
  const float* beta  = (const float*)d_in[12];
  float* out = (float*)d_out;

  char* ws = (char*)d_ws;
  const size_t MB = 1u << 20;
  ushort_t* xb  = (ushort_t*)(ws);
  ushort_t* wtq = (ushort_t*)(ws + 16 * MB);
  ushort_t* wtk = (ushort_t*)(ws + 18 * MB);
  ushort_t* wtv = (ushort_t*)(ws + 20 * MB);
  ushort_t* wto = (ushort_t*)(ws + 22 * MB);
  ushort_t* qb  = (ushort_t*)(ws + 24 * MB);
  ushort_t* kb  = (ushort_t*)(ws + 40 * MB);
  ushort_t* vtb = (ushort_t*)(ws + 56 * MB);
  ushort_t* ao  = (ushort_t*)(ws);
  float*    y   = (float*)(ws + 24 * MB);
  float*    s1  = (float*)(ws + 56 * MB);
  float*    s2  = (float*)(ws + 56 * MB + 4096);

  wtr_k<<<dim3(16, 16), 256, 0, stream>>>(Wq, wtq, 0);
  wtr_k<<<dim3(16, 16), 256, 0, stream>>>(Wk, wtk, 0);
  wtr_k<<<dim3(16, 16), 256, 0, stream>>>(Wv, wtv, 0);
  wtr_k<<<dim3(16, 16), 256, 0, stream>>>(Wo, wto, 1);

  // q pre-scaled by SCALE*log2(e) so attention logits are already exp2-domain
  const float QSC = SCALE_ * 1.44269504088896f;
  cvtx_k<<<4096, 256, 0, stream>>>(Q, xb);
  gemm_proj<<<dim3(64, 8), 256, 0, stream>>>(xb, wtq, bq, qb, QSC);
  cvtx_k<<<4096, 256, 0, stream>>>(Kin, xb);
  gemm_proj<<<dim3(64, 8), 256, 0, stream>>>(xb, wtk, bk, kb, 1.0f);
  cvtx_k<<<4096, 256, 0, stream>>>(Vin, xb);
  gemm_projT<<<dim3(64, 8), 256, 0, stream>>>(xb, wtv, bv, vtb);

  attn_k<<<dim3(16, 16, 4), 256, 0, stream>>>(qb, kb, vtb, ao);
  gemm_oproj<<<dim3(64, 8), 256, 0, stream>>>(ao, wto, bo, Q, y);

  hipMemsetAsync(ws + 56 * MB, 0, 8192, stream);
  stats_k<<<256, 256, 0, stream>>>(y, s1, s2);
  norm_k<<<dim3(32, 16, 4), 256, 0, stream>>>(y, s1, s2, gamma, beta, out);
}

// Round 3
// 389.906 us; speedup vs baseline: 1.1770x; 1.0274x over previous
//
#include <hip/hip_runtime.h>

#define B_ 4
#define S_ 2048
#define D_ 1024
#define H_ 16
#define SCALE_ 0.03125f
#define EPS_ 1e-5f
#define NBS_ 8192   // B*S

typedef unsigned short ushort_t;
typedef __attribute__((ext_vector_type(8))) short short8;
typedef __attribute__((ext_vector_type(4))) short short4v;
typedef __attribute__((ext_vector_type(4))) float floatx4;
typedef __attribute__((ext_vector_type(2))) unsigned int uint2v;

__device__ __forceinline__ ushort_t f2bf(float f) {
  union { float f; unsigned u; } v; v.f = f;
  unsigned r = v.u + 0x7fffu + ((v.u >> 16) & 1u);
  return (ushort_t)(r >> 16);
}

__device__ __forceinline__ float fast_exp2(float x) {
#if __has_builtin(__builtin_amdgcn_exp2f)
  return __builtin_amdgcn_exp2f(x);
#else
  return __expf(x * 0.6931471805599453f);
#endif
}

// packed f32x2 -> bf16x2 (RNE), one VALU op; src0 -> low half
__device__ __forceinline__ unsigned cvt_pk_bf16(float a, float b) {
  unsigned r;
  asm("v_cvt_pk_bf16_f32 %0, %1, %2" : "=v"(r) : "v"(a), "v"(b));
  return r;
}

__device__ __forceinline__ short8 cvt8(float4 a, float4 b) {
  short8 r;
  r[0] = (short)f2bf(a.x); r[1] = (short)f2bf(a.y);
  r[2] = (short)f2bf(a.z); r[3] = (short)f2bf(a.w);
  r[4] = (short)f2bf(b.x); r[5] = (short)f2bf(b.y);
  r[6] = (short)f2bf(b.z); r[7] = (short)f2bf(b.w);
  return r;
}

// async global->LDS, 16B per lane; lds dest = wave-uniform base + lane*16
__device__ __forceinline__ void gload16(const void* g, void* l) {
  __builtin_amdgcn_global_load_lds(
      (const __attribute__((address_space(1))) unsigned int*)g,
      (__attribute__((address_space(3))) unsigned int*)l, 16, 0, 0);
}

// ---------------------------------------------------------------------------
// cvtx_k: f32 -> bf16 elementwise (8 elems/thread)
// ---------------------------------------------------------------------------
__global__ __launch_bounds__(256) void cvtx_k(const float* __restrict__ src,
                                              ushort_t* __restrict__ dst)
{
  size_t i = ((size_t)blockIdx.x * 256 + threadIdx.x) * 8;
  float4 a = *(const float4*)(src + i);
  float4 b = *(const float4*)(src + i + 4);
  *(short8*)(dst + i) = cvt8(a, b);
}

// ---------------------------------------------------------------------------
// wtr_k: weight transpose f32 -> bf16 N x K (k-contiguous).
// mode 0: src = W[h][d][n] ([H,1024,64]); dst[c=h*64+n][d]
// mode 1: src = Wo[c][d] ([1024,1024]);  dst[d][c]
// ---------------------------------------------------------------------------
__global__ __launch_bounds__(256) void wtr_k(const float* __restrict__ src,
                                             ushort_t* __restrict__ dst, int mode)
{
  __shared__ float t[64][65];
  const int tr = blockIdx.x, tc = blockIdx.y;
  const float* sb; int sld;
  if (mode == 0) { sb = src + (size_t)tr * 65536 + (size_t)tc * 64 * 64; sld = 64; }
  else           { sb = src + (size_t)tc * 64 * 1024 + (size_t)tr * 64;  sld = 1024; }
  const int tid = threadIdx.x;
  const int rr = tid >> 2, cs = (tid & 3) * 16;
  const float* p = sb + (size_t)rr * sld + cs;
#pragma unroll
  for (int j = 0; j < 16; ++j) t[rr][cs + j] = p[j];
  __syncthreads();
  ushort_t* dp = dst + (size_t)(tr * 64 + rr) * 1024 + tc * 64 + cs;
#pragma unroll
  for (int j = 0; j < 16; ++j) dp[j] = f2bf(t[cs + j][rr]);
}

// ---------------------------------------------------------------------------
// Shared GEMM mainloop: 128x128 tile, BK=64, double-buffered LDS, one barrier
// per K-step, stage-before-compute (attn_k-proven structure).
// LDS layout per buffer: [128 rows][128 B], physical kbyte = logical ^
// ((row&7)<<4).  Staging pre-swizzles the GLOBAL source so LDS dest stays
// linear for global_load_lds (rule: both-sides-or-neither).
// ---------------------------------------------------------------------------
__device__ __forceinline__ void gemm_mainloop(
    const ushort_t* __restrict__ A, const ushort_t* __restrict__ Bw,
    ushort_t* As, ushort_t* Bs,   // each [2][128*64] elems (32 KiB)
    int m0, int n0, int wv, int lane, floatx4 acc[4][4])
{
  const int quad = lane >> 4, l16 = lane & 15;
  const int wm = wv & 1, wn = wv >> 1;
  const int r8 = lane >> 3;                 // row within 8-row group
  const int kx = ((lane & 7) ^ r8) * 8;     // pre-swizzled k-elem offset

  auto stage = [&](int buf, int k0) {
#pragma unroll
    for (int j = 0; j < 4; ++j) {
      const int rb = (wv * 4 + j) * 8;      // 8 rows per gload16
      gload16(A + (size_t)(m0 + rb + r8) * 1024 + k0 + kx,
              (char*)As + buf * 16384 + rb * 128);
      gload16(Bw + (size_t)(n0 + rb + r8) * 1024 + k0 + kx,
              (char*)Bs + buf * 16384 + rb * 128);
    }
  };

  stage(0, 0);
  __syncthreads();    // implicit vmcnt(0) drain

  const int swz = (l16 & 7) << 4;
  for (int it = 0; it < 16; ++it) {
    const int cur = it & 1;
    if (it < 15) stage(cur ^ 1, (it + 1) * 64);
    const char* Ab = (const char*)As + cur * 16384;
    const char* Bb = (const char*)Bs + cur * 16384;
#pragma unroll
    for (int hf = 0; hf < 2; ++hf) {
      short8 af[4], bf[4];
      const int C = (hf * 64 + quad * 16) ^ swz;
#pragma unroll
      for (int i = 0; i < 4; ++i)
        af[i] = *(const short8*)(Ab + (wm * 64 + i * 16 + l16) * 128 + C);
#pragma unroll
      for (int i = 0; i < 4; ++i)
        bf[i] = *(const short8*)(Bb + (wn * 64 + i * 16 + l16) * 128 + C);
#pragma unroll
      for (int mi = 0; mi < 4; ++mi)
#pragma unroll
        for (int ni = 0; ni < 4; ++ni)
          acc[mi][ni] = __builtin_amdgcn_mfma_f32_16x16x32_bf16(
              af[mi], bf[ni], acc[mi][ni], 0, 0, 0);
    }
    __syncthreads();  // drains prefetch + LDS reads; protects buffer reuse
  }
}

// ---------------------------------------------------------------------------
// gemm_proj: C[m][c] = (A[m][:].Bw[c][:] + bias[c]) * scale -> [B][H][S][64]
// ---------------------------------------------------------------------------
__global__ __launch_bounds__(256) void gemm_proj(
    const ushort_t* __restrict__ A, const ushort_t* __restrict__ Bw,
    const float* __restrict__ bias, ushort_t* __restrict__ outp, float scale)
{
  __shared__ ushort_t As[2 * 128 * 64];
  __shared__ ushort_t Bs[2 * 128 * 64];
  const int tid = threadIdx.x;
  const int wv = tid >> 6, lane = tid & 63, quad = lane >> 4, l16 = lane & 15;
  const int m0 = blockIdx.x * 128, n0 = blockIdx.y * 128;
  const int wm = wv & 1, wn = wv >> 1;

  floatx4 acc[4][4];
#pragma unroll
  for (int i = 0; i < 4; ++i)
#pragma unroll
    for (int j = 0; j < 4; ++j) acc[i][j] = (floatx4){0.f, 0.f, 0.f, 0.f};

  gemm_mainloop(A, Bw, As, Bs, m0, n0, wv, lane, acc);

  const int b = m0 >> 11;
  const int sbase = (m0 & 2047) + wm * 64;
#pragma unroll
  for (int ni = 0; ni < 4; ++ni) {
    const int c = n0 + wn * 64 + ni * 16 + l16;
    const int h = c >> 6, nn = c & 63;
    const float bs = bias[c];
    ushort_t* op = outp + (size_t)(b * 16 + h) * 2048 * 64 + nn;
#pragma unroll
    for (int mi = 0; mi < 4; ++mi)
#pragma unroll
      for (int r = 0; r < 4; ++r) {
        int s = sbase + mi * 16 + quad * 4 + r;
        op[(size_t)s * 64] = f2bf((acc[mi][ni][r] + bs) * scale);
      }
  }
}

// ---------------------------------------------------------------------------
// gemm_projT: same GEMM but epilogue writes V^T: out[(b*16+h)][dv][s]
// ---------------------------------------------------------------------------
__global__ __launch_bounds__(256) void gemm_projT(
    const ushort_t* __restrict__ A, const ushort_t* __restrict__ Bw,
    const float* __restrict__ bias, ushort_t* __restrict__ outp)
{
  __shared__ ushort_t As[2 * 128 * 64];
  __shared__ ushort_t Bs[2 * 128 * 64];
  const int tid = threadIdx.x;
  const int wv = tid >> 6, lane = tid & 63, quad = lane >> 4, l16 = lane & 15;
  const int m0 = blockIdx.x * 128, n0 = blockIdx.y * 128;
  const int wm = wv & 1, wn = wv >> 1;

  floatx4 acc[4][4];
#pragma unroll
  for (int i = 0; i < 4; ++i)
#pragma unroll
    for (int j = 0; j < 4; ++j) acc[i][j] = (floatx4){0.f, 0.f, 0.f, 0.f};

  gemm_mainloop(A, Bw, As, Bs, m0, n0, wv, lane, acc);

  const int b = m0 >> 11;
  const int sbase = (m0 & 2047) + wm * 64;
#pragma unroll
  for (int ni = 0; ni < 4; ++ni) {
    const int c = n0 + wn * 64 + ni * 16 + l16;
    const int h = c >> 6, nn = c & 63;
    const float bs = bias[c];
    ushort_t* op = outp + ((size_t)(b * 16 + h) * 64 + nn) * 2048;
#pragma unroll
    for (int mi = 0; mi < 4; ++mi) {
      int s0v = sbase + mi * 16 + quad * 4;
      short4v p;
#pragma unroll
      for (int r = 0; r < 4; ++r) p[r] = (short)f2bf(acc[mi][ni][r] + bs);
      *(short4v*)(op + s0v) = p;
    }
  }
}

// ---------------------------------------------------------------------------
// gemm_oproj: y[m][d] = ao[m][:].Wt_o[d][:] + bo[d] + resid[m][d]  (f32 out)
// Fused batch-stats: per-channel sum/sumsq accumulated via quad shuffle-
// reduce + one atomicAdd per column per wave-half (replaces stats_k).
// ---------------------------------------------------------------------------
__global__ __launch_bounds__(256) void gemm_oproj(
    const ushort_t* __restrict__ A, const ushort_t* __restrict__ Bw,
    const float* __restrict__ bo, const float* __restrict__ resid,
    float* __restrict__ y, float* __restrict__ s1, float* __restrict__ s2)
{
  __shared__ ushort_t As[2 * 128 * 64];
  __shared__ ushort_t Bs[2 * 128 * 64];
  const int tid = threadIdx.x;
  const int wv = tid >> 6, lane = tid & 63, quad = lane >> 4, l16 = lane & 15;
  const int m0 = blockIdx.x * 128, n0 = blockIdx.y * 128;
  const int wm = wv & 1, wn = wv >> 1;

  floatx4 acc[4][4];
#pragma unroll
  for (int i = 0; i < 4; ++i)
#pragma unroll
    for (int j = 0; j < 4; ++j) acc[i][j] = (floatx4){0.f, 0.f, 0.f, 0.f};

  gemm_mainloop(A, Bw, As, Bs, m0, n0, wv, lane, acc);

  const int mb = m0 + wm * 64;
#pragma unroll
  for (int ni = 0; ni < 4; ++ni) {
    const int d = n0 + wn * 64 + ni * 16 + l16;
    const float bs = bo[d];
    float ps1 = 0.f, ps2 = 0.f;
#pragma unroll
    for (int mi = 0; mi < 4; ++mi)
#pragma unroll
      for (int r = 0; r < 4; ++r) {
        int m = mb + mi * 16 + quad * 4 + r;
        float val = acc[mi][ni][r] + bs + resid[(size_t)m * 1024 + d];
        y[(size_t)m * 1024 + d] = val;
        ps1 += val;
        ps2 += val * val;
      }
    // reduce the 64-row (this wave-half) partial across the 4 quads
    ps1 += __shfl_xor(ps1, 16); ps1 += __shfl_xor(ps1, 32);
    ps2 += __shfl_xor(ps2, 16); ps2 += __shfl_xor(ps2, 32);
    if (quad == 0) {
      atomicAdd(&s1[d], ps1);
      atomicAdd(&s2[d], ps2);
    }
  }
}

// ---------------------------------------------------------------------------
// attn_k v5: swapped QK^T; P packed via v_cvt_pk_bf16_f32 (1 op / 2 vals);
//   P swizzle includes bit3 -> writes AND reads conflict-free; P reads are
//   2x ds_read_b64 (lo, lo^8).  Row-sum via ones-MFMA (no VALU adds, no
//   epilogue shuffles).
// LDS byte map: K dbuf [0,16384) | V dbuf [16384,32768) | P [32768,49152)
// ---------------------------------------------------------------------------
__global__ __launch_bounds__(256, 3) void attn_k(
    const ushort_t* __restrict__ q, const ushort_t* __restrict__ k,
    const ushort_t* __restrict__ vt, ushort_t* __restrict__ ao)
{
  __shared__ ushort_t lds[24576];   // 48 KiB
  char* ldsb = (char*)lds;
  const int tid = threadIdx.x;
  const int wv = tid >> 6, lane = tid & 63, quad = lane >> 4, l16 = lane & 15;
  const int q0 = blockIdx.x * 128, h = blockIdx.y, b = blockIdx.z;
  const size_t bh = (size_t)(b * H_ + h) * S_;
  const ushort_t* vb = vt + (size_t)(b * H_ + h) * 64 * S_;

  // Q fragments (held all kernel): aq[rb][half]; q pre-scaled by SCALE*log2e
  short8 aq[2][2];
#pragma unroll
  for (int rb = 0; rb < 2; ++rb) {
    const ushort_t* qrow = q + (bh + q0 + wv * 32 + rb * 16 + l16) * 64;
    aq[rb][0] = *(const short8*)(qrow + quad * 8);
    aq[rb][1] = *(const short8*)(qrow + 32 + quad * 8);
  }

  // all-ones bf16 B fragment for the row-sum MFMA
  short8 ones;
#pragma unroll
  for (int j = 0; j < 8; ++j) ones[j] = (short)0x3F80;

  floatx4 o[2][4];
  floatx4 accl[2];
#pragma unroll
  for (int rb = 0; rb < 2; ++rb) {
#pragma unroll
    for (int cb = 0; cb < 4; ++cb) o[rb][cb] = (floatx4){0.f, 0.f, 0.f, 0.f};
    accl[rb] = (floatx4){0.f, 0.f, 0.f, 0.f};
  }

  // P addressing: unswizzled byte of P[q=l16][t] = q*128 + t*2; swizzle
  // XORs bits 3..6 with row bits -> every 16-lane group covers all 32 banks
  // on both the b64 writes and the b64 reads.
  const int swz = ((l16 & 7) << 4) | (l16 & 8);
  const int q8 = quad * 8;
  const int pb = 32768 + wv * 4096 + l16 * 128;   // per-wave, per-row base

  // stage(nb, t0): K block idx -> bytes nb*8192 + idx*1024 (idx = cb*2+hf)
  //                V block     -> bytes 16384 + nb*8192 + (idx-8)*1024
  auto stage = [&](int nb, int t0) {
#pragma unroll
    for (int i = 0; i < 4; ++i) {
      const int idx = wv * 4 + i;
      const int cb = (idx >> 1) & 3, hf = idx & 1;
      if (idx < 8)
        gload16(k + (bh + t0 + cb * 16 + l16) * 64 + hf * 32 + quad * 8,
                (char*)lds + nb * 8192 + idx * 1024);
      else
        gload16(vb + (size_t)(cb * 16 + l16) * S_ + t0 + hf * 32 + quad * 8,
                (char*)lds + 16384 + nb * 8192 + (idx - 8) * 1024);
    }
  };

  stage(0, 0);
  asm volatile("s_waitcnt vmcnt(0)" ::: "memory");
  __syncthreads();

  for (int t0 = 0; t0 < S_; t0 += 64) {
    const int nb = (t0 >> 6) & 1;
    const ushort_t* KsC = lds + nb * 4096;          // ushort offsets
    const ushort_t* VsC = lds + 8192 + nb * 4096;
    if (t0 + 64 < S_) stage(nb ^ 1, t0 + 64);

    // QK^T swapped: sc = mfma(K, Q) -> lane holds S[t=cb*16+quad*4+r][q=l16]
    floatx4 sc[2][4];
#pragma unroll
    for (int rb = 0; rb < 2; ++rb)
#pragma unroll
      for (int cb = 0; cb < 4; ++cb) sc[rb][cb] = (floatx4){0.f, 0.f, 0.f, 0.f};
    __builtin_amdgcn_s_setprio(1);
#pragma unroll
    for (int hf = 0; hf < 2; ++hf) {
      short8 bk[4];
#pragma unroll
      for (int cb = 0; cb < 4; ++cb)
        bk[cb] = *(const short8*)&KsC[(cb * 2 + hf) * 512 + lane * 8];
#pragma unroll
      for (int rb = 0; rb < 2; ++rb)
#pragma unroll
        for (int cb = 0; cb < 4; ++cb)
          sc[rb][cb] = __builtin_amdgcn_mfma_f32_16x16x32_bf16(
              bk[cb], aq[rb][hf], sc[rb][cb], 0, 0, 0);
    }
    __builtin_amdgcn_s_setprio(0);

    // V fragments once per tile (both hf, both rb use them)
    short8 bvf[2][4];
#pragma unroll
    for (int hf = 0; hf < 2; ++hf)
#pragma unroll
      for (int cb = 0; cb < 4; ++cb)
        bvf[hf][cb] = *(const short8*)&VsC[(cb * 2 + hf) * 512 + lane * 8];

    // exp2 + packed cvt -> 4x ds_write_b64 per rb (conflict-free swizzle)
#pragma unroll
    for (int rb = 0; rb < 2; ++rb)
#pragma unroll
      for (int cb = 0; cb < 4; ++cb) {
        float p0 = fast_exp2(sc[rb][cb][0]);
        float p1 = fast_exp2(sc[rb][cb][1]);
        float p2 = fast_exp2(sc[rb][cb][2]);
        float p3 = fast_exp2(sc[rb][cb][3]);
        uint2v w;
        w[0] = cvt_pk_bf16(p0, p1);
        w[1] = cvt_pk_bf16(p2, p3);
        *(uint2v*)(ldsb + pb + rb * 2048 + ((cb * 32 + q8) ^ swz)) = w;
      }
    asm volatile("s_waitcnt lgkmcnt(0)" ::: "memory");
    __builtin_amdgcn_sched_barrier(0);

    // PV + row-sum: ap = A-fragment of P (row q=l16, k = hf*32+quad*8+j)
    __builtin_amdgcn_s_setprio(1);
#pragma unroll
    for (int rb = 0; rb < 2; ++rb)
#pragma unroll
      for (int hf = 0; hf < 2; ++hf) {
        const char* pr = ldsb + pb + rb * 2048;
        const int lo = (hf * 64 + quad * 16) ^ swz;
        short4v a0 = *(const short4v*)(pr + lo);
        short4v a1 = *(const short4v*)(pr + (lo ^ 8));
        short8 ap;
        ap[0] = a0[0]; ap[1] = a0[1]; ap[2] = a0[2]; ap[3] = a0[3];
        ap[4] = a1[0]; ap[5] = a1[1]; ap[6] = a1[2]; ap[7] = a1[3];
#pragma unroll
        for (int cb = 0; cb < 4; ++cb)
          o[rb][cb] = __builtin_amdgcn_mfma_f32_16x16x32_bf16(
              ap, bvf[hf][cb], o[rb][cb], 0, 0, 0);
        accl[rb] = __builtin_amdgcn_mfma_f32_16x16x32_bf16(
            ap, ones, accl[rb], 0, 0, 0);
      }
    __builtin_amdgcn_s_setprio(0);

    asm volatile("s_waitcnt vmcnt(0)" ::: "memory");  // prefetch landed
    __syncthreads();
  }

  // epilogue: accl[rb][r] = full row sum for q-row quad*4+r (+rb*16+wv*32).
  float linv[2][4];
#pragma unroll
  for (int rb = 0; rb < 2; ++rb)
#pragma unroll
    for (int r = 0; r < 4; ++r)
      linv[rb][r] = 1.f / accl[rb][r];
#pragma unroll
  for (int rb = 0; rb < 2; ++rb)
#pragma unroll
    for (int cb = 0; cb < 4; ++cb)
#pragma unroll
      for (int r = 0; r < 4; ++r) {
        float val = o[rb][cb][r] * linv[rb][r];
        size_t idx = (size_t)(b * S_ + q0 + wv * 32 + rb * 16 + quad * 4 + r) * 1024
                     + h * 64 + cb * 16 + l16;
        ao[idx] = f2bf(val);
      }
}

// ---------------------------------------------------------------------------
// K5: batchnorm affine + 64x64 transpose -> out[b][d][s] (f32)
// ---------------------------------------------------------------------------
__global__ __launch_bounds__(256) void norm_k(
    const float* __restrict__ y, const float* __restrict__ s1,
    const float* __restrict__ s2, const float* __restrict__ gamma,
    const float* __restrict__ beta, float* __restrict__ out)
{
  __shared__ float tile[64][65];
  __shared__ float scl[64], sft[64];
  const int tid = threadIdx.x;
  const int s0 = blockIdx.x * 64, d0 = blockIdx.y * 64, b = blockIdx.z;

  if (tid < 64) {
    int d = d0 + tid;
    float mean = s1[d] * (1.f / (float)NBS_);
    float var = s2[d] * (1.f / (float)NBS_) - mean * mean;
    float rstd = rsqrtf(var + EPS_);
    float g = gamma[d];
    scl[tid] = rstd * g;
    sft[tid] = beta[d] - mean * rstd * g;
  }
  __syncthreads();

  const int si = tid >> 2, dc = (tid & 3) * 16;
  const float* row = y + (size_t)(b * S_ + s0 + si) * D_ + d0 + dc;
#pragma unroll
  for (int j = 0; j < 16; ++j)
    tile[si][dc + j] = row[j] * scl[dc + j] + sft[dc + j];
  __syncthreads();

  const int di = tid >> 2, sg = (tid & 3) * 16;
  float* dst = out + (size_t)(b * D_ + d0 + di) * S_ + s0 + sg;
#pragma unroll
  for (int jj = 0; jj < 4; ++jj) {
    float4 p;
    p.x = tile[sg + jj * 4 + 0][di];
    p.y = tile[sg + jj * 4 + 1][di];
    p.z = tile[sg + jj * 4 + 2][di];
    p.w = tile[sg + jj * 4 + 3][di];
    *(float4*)(dst + jj * 4) = p;
  }
}

// ---------------------------------------------------------------------------
extern "C" void kernel_launch(void* const* d_in, const int* in_sizes, int n_in,
                              void* d_out, int out_size, void* d_ws, size_t ws_size,
                              hipStream_t stream)
{
  (void)in_sizes; (void)n_in; (void)out_size; (void)ws_size;
  const float* Q     = (const float*)d_in[0];
  const float* Kin   = (const float*)d_in[1];
  const float* Vin   = (const float*)d_in[2];
  const float* Wq    = (const float*)d_in[3];
  const float* bq    = (const float*)d_in[4];
  const float* Wk    = (const float*)d_in[5];
  const float* bk    = (const float*)d_in[6];
  const float* Wv    = (const float*)d_in[7];
  const float* bv    = (const float*)d_in[8];
  const float* Wo    = (const float*)d_in[9];
  const float* bo    = (const float*)d_in[10];
  const float* gamma = (const float*)d_in[11];
  const float* beta  = (const float*)d_in[12];
  float* out = (float*)d_out;

  char* ws = (char*)d_ws;
  const size_t MB = 1u << 20;
  ushort_t* xb  = (ushort_t*)(ws);
  ushort_t* wtq = (ushort_t*)(ws + 16 * MB);
  ushort_t* wtk = (ushort_t*)(ws + 18 * MB);
  ushort_t* wtv = (ushort_t*)(ws + 20 * MB);
  ushort_t* wto = (ushort_t*)(ws + 22 * MB);
  ushort_t* qb  = (ushort_t*)(ws + 24 * MB);
  ushort_t* kb  = (ushort_t*)(ws + 40 * MB);
  ushort_t* vtb = (ushort_t*)(ws + 56 * MB);
  ushort_t* ao  = (ushort_t*)(ws);
  float*    y   = (float*)(ws + 24 * MB);
  float*    s1  = (float*)(ws + 56 * MB);
  float*    s2  = (float*)(ws + 56 * MB + 4096);

  wtr_k<<<dim3(16, 16), 256, 0, stream>>>(Wq, wtq, 0);
  wtr_k<<<dim3(16, 16), 256, 0, stream>>>(Wk, wtk, 0);
  wtr_k<<<dim3(16, 16), 256, 0, stream>>>(Wv, wtv, 0);
  wtr_k<<<dim3(16, 16), 256, 0, stream>>>(Wo, wto, 1);

  // q pre-scaled by SCALE*log2(e) so attention logits are already exp2-domain
  const float QSC = SCALE_ * 1.44269504088896f;
  cvtx_k<<<4096, 256, 0, stream>>>(Q, xb);
  gemm_proj<<<dim3(64, 8), 256, 0, stream>>>(xb, wtq, bq, qb, QSC);
  cvtx_k<<<4096, 256, 0, stream>>>(Kin, xb);
  gemm_proj<<<dim3(64, 8), 256, 0, stream>>>(xb, wtk, bk, kb, 1.0f);
  cvtx_k<<<4096, 256, 0, stream>>>(Vin, xb);
  gemm_projT<<<dim3(64, 8), 256, 0, stream>>>(xb, wtv, bv, vtb);

  attn_k<<<dim3(16, 16, 4), 256, 0, stream>>>(qb, kb, vtb, ao);

  // s1/s2 overlap vtb (dead after attn_k); zero them before fused oproj
  hipMemsetAsync(ws + 56 * MB, 0, 8192, stream);
  gemm_oproj<<<dim3(64, 8), 256, 0, stream>>>(ao, wto, bo, Q, y, s1, s2);

  norm_k<<<dim3(32, 16, 4), 256, 0, stream>>>(y, s1, s2, gamma, beta, out);
}